// Round 4
// baseline (288.539 us; speedup 1.0000x reference)
//
#include <hip/hip_runtime.h>
#include <hip/hip_bf16.h>
#include <math.h>

// Problem constants (B=4096 rows, D=768 features)
#define B_ROWS 4096
#define D_DIM  768

#define BM 128
#define BN 128
#define BK 64              // 64 bf16 = 128 B per tile row = 8 x 16B chunks
#define NKT (D_DIM / BK)   // 12 K-tiles
#define NBLK (B_ROWS / BM) // 32 tile-blocks per dim
#define GRID_TILES (NBLK * NBLK)

typedef __attribute__((ext_vector_type(8))) short bf16x8;  // 8 bf16 = 4 VGPRs (MFMA A/B frag)
typedef __attribute__((ext_vector_type(4))) float f32x4;   // MFMA C/D frag

__device__ __forceinline__ unsigned short f32_to_bf16(float x) {
    // round-to-nearest-even; inputs are finite normals
    unsigned int u = __float_as_uint(x);
    return (unsigned short)((u + 0x7fffu + ((u >> 16) & 1u)) >> 16);
}

// K1: per-row stats + fp32->bf16 conversion. One WAVE per row (4 rows/block).
__global__ void __launch_bounds__(256) rowstats_kernel(
    const float* __restrict__ P, const float* __restrict__ T,
    unsigned short* __restrict__ Pb, unsigned short* __restrict__ Tb,
    float* __restrict__ p_sq, float* __restrict__ t_sq,
    float* __restrict__ diagl, float* __restrict__ magr,
    float* __restrict__ rowsum, unsigned int* __restrict__ counter)
{
    if (blockIdx.x == 0 && threadIdx.x == 0) *counter = 0u;
    const int wave = threadIdx.x >> 6, lane = threadIdx.x & 63;
    const int i = blockIdx.x * 4 + wave;
    const f32x4* prow = (const f32x4*)(P + (size_t)i * D_DIM);
    const f32x4* trow = (const f32x4*)(T + (size_t)i * D_DIM);
    ushort4* pbrow = (ushort4*)(Pb + (size_t)i * D_DIM);
    ushort4* tbrow = (ushort4*)(Tb + (size_t)i * D_DIM);

    float psq = 0.f, tsq = 0.f, cr = 0.f, l1 = 0.f, tm = 0.f;
    #pragma unroll
    for (int u = 0; u < 3; ++u) {         // 192 float4 per row / 64 lanes
        const int c4 = u * 64 + lane;
        f32x4 p = prow[c4], t = trow[c4];
        #pragma unroll
        for (int k = 0; k < 4; ++k) {
            psq += p[k] * p[k]; tsq += t[k] * t[k]; cr += p[k] * t[k];
            l1 += fabsf(p[k] - t[k]); tm += fabsf(t[k]);
        }
        pbrow[c4] = make_ushort4(f32_to_bf16(p[0]), f32_to_bf16(p[1]),
                                 f32_to_bf16(p[2]), f32_to_bf16(p[3]));
        tbrow[c4] = make_ushort4(f32_to_bf16(t[0]), f32_to_bf16(t[1]),
                                 f32_to_bf16(t[2]), f32_to_bf16(t[3]));
    }
    #pragma unroll
    for (int m = 1; m < 64; m <<= 1) {
        psq += __shfl_xor(psq, m, 64);
        tsq += __shfl_xor(tsq, m, 64);
        cr  += __shfl_xor(cr,  m, 64);
        l1  += __shfl_xor(l1,  m, 64);
        tm  += __shfl_xor(tm,  m, 64);
    }
    if (lane == 0) {
        p_sq[i] = psq;
        t_sq[i] = tsq;
        float sq = fmaxf(psq + tsq - 2.0f * cr, 0.0f);
        diagl[i] = -sqrtf(sq) * 10.0f;    // logit_ii = -dist/0.1 (the LSE shift)
        magr[i]  = l1 / tm;
        rowsum[i] = 0.0f;
    }
}

// K2: bf16-MFMA cross GEMM (128x128 tile) + shifted-exp row-sum epilogue
// + fused final reduction (last block).
//
// K-loop structure (the fix for R3's exposed latency): global loads go to
// VGPRs (no LDS aliasing -> compiler can't pin them with vmcnt(0) at the
// barrier); the vmcnt wait lands before NEXT iteration's ds_write, i.e.
// after a full compute phase. Barriers drain only lgkmcnt (fast).
//   load(0)->regs
//   loop: [barrier] ds_write regs; load(kt+1)->regs; barrier; compute(kt)
// Single 32KB LDS buffer -> ~3 blocks/CU.
// LDS chunk-XOR swizzle (slot = chunk ^ row&7, 16B units): 0 bank conflicts
// (verified R2/R3); writes cover each bank 2x per 16 lanes (free, m136).
__global__ void __launch_bounds__(256) lse_gemm_kernel(
    const unsigned short* __restrict__ Pb, const unsigned short* __restrict__ Tb,
    const float* __restrict__ p_sq, const float* __restrict__ t_sq,
    const float* __restrict__ diagl, const float* __restrict__ magr,
    float* __restrict__ rowsum, unsigned int* __restrict__ counter,
    float* __restrict__ out)
{
    __shared__ __align__(16) unsigned short As[BM * BK];  // 16 KB
    __shared__ __align__(16) unsigned short Bs[BN * BK];  // 16 KB

    const int tid = threadIdx.x;

    // XCD-aware swizzle: HW round-robins linear wg id over 8 XCDs (flat%8).
    // Group 8x8 tiles (3.1 MB working set < 4 MiB L2) onto one XCD.
    const int flat = blockIdx.y * NBLK + blockIdx.x;
    const int xcd  = flat & 7;
    const int s    = flat >> 3;                 // 0..127: slot within XCD
    const int g    = xcd + ((s >> 6) << 3);     // group 0..15
    const int w    = s & 63;                    // tile within 8x8 group
    const int i0   = (((g >> 2) << 3) + (w >> 3)) * BM;  // P row block
    const int j0   = (((g & 3) << 3) + (w & 7)) * BN;    // T row block

    const int lane  = tid & 63;
    const int wave  = tid >> 6;
    const int wm    = wave >> 1, wn = wave & 1;    // 2x2 wave grid
    const int row16 = lane & 15, quad = lane >> 4;
    const int m_base = wm * 64, n_base = wn * 64;
    const int swz = (quad ^ (row16 & 7)) << 4;  // ds_read swizzled byte offset

    // staging map: thread covers rows r0+32*it (it=0..3), chunk c8 (16B) of
    // each row; writes it to swizzled LDS slot c8 ^ (row&7).
    const int c8 = tid & 7;            // chunk column 0..7
    const int r0 = tid >> 3;           // base row 0..31
    const int sw = c8 ^ (r0 & 7);      // (32*it doesn't change row&7)
    const int4* gpA = (const int4*)Pb + (size_t)(i0 + r0) * (D_DIM / 8) + c8;
    const int4* gpB = (const int4*)Tb + (size_t)(j0 + r0) * (D_DIM / 8) + c8;
    int4* lwA = (int4*)&As[r0 * 64 + sw * 8];   // +it*256 (int4) per 32 rows
    int4* lwB = (int4*)&Bs[r0 * 64 + sw * 8];

    f32x4 acc[4][4];
    #pragma unroll
    for (int a = 0; a < 4; ++a)
        #pragma unroll
        for (int b = 0; b < 4; ++b)
            acc[a][b] = (f32x4){0.f, 0.f, 0.f, 0.f};

    int4 ps[4], tsg[4];
    #pragma unroll
    for (int it = 0; it < 4; ++it) {            // prologue: tile 0 -> regs
        ps[it]  = gpA[it * 3072];               // 32 rows * 96 int4/row
        tsg[it] = gpB[it * 3072];
    }

    const char* Ab = (const char*)As;
    const char* Bb = (const char*)Bs;

    for (int ktile = 0; ktile < NKT; ++ktile) {
        if (ktile) __syncthreads();   // all waves done reading LDS (lgkm only)
        #pragma unroll
        for (int it = 0; it < 4; ++it) {        // regs -> LDS (vmcnt wait here)
            lwA[it * 256] = ps[it];
            lwB[it * 256] = tsg[it];
        }
        if (ktile + 1 < NKT) {                  // prefetch next tile -> regs
            const int ko = (ktile + 1) * 8;     // 8 int4 per BK step
            #pragma unroll
            for (int it = 0; it < 4; ++it) {
                ps[it]  = gpA[it * 3072 + ko];
                tsg[it] = gpB[it * 3072 + ko];
            }
        }
        __syncthreads();                        // LDS writes visible

        #pragma unroll
        for (int ks = 0; ks < BK; ks += 32) {
            const int kx = ks ? 64 : 0;   // chunk+4 == slot^4 == byte addr^64
            bf16x8 a[4], b[4];
            #pragma unroll
            for (int mt = 0; mt < 4; ++mt) {
                const int off = (m_base + mt * 16 + row16) * 128 + swz;
                a[mt] = *(const bf16x8*)(Ab + (off ^ kx));
            }
            #pragma unroll
            for (int nt = 0; nt < 4; ++nt) {
                const int off = (n_base + nt * 16 + row16) * 128 + swz;
                b[nt] = *(const bf16x8*)(Bb + (off ^ kx));
            }
            #pragma unroll
            for (int mt = 0; mt < 4; ++mt)
                #pragma unroll
                for (int nt = 0; nt < 4; ++nt)
                    acc[mt][nt] = __builtin_amdgcn_mfma_f32_16x16x32_bf16(
                        a[mt], b[nt], acc[mt][nt], 0, 0, 0);
        }
    }

    // Epilogue: C/D layout col=lane&15, row=quad*4+reg (m89/m91-verified).
    // term = exp(logit_ij - logit_ii) via exp2f; max shifted log2-exp ~99 < 127.
    const float NT_LOG2E = -14.4269504089f;   // -(1/TEMP) * log2(e)
    const float LOG2E    = 1.44269504089f;
    float tsq_l[4];
    #pragma unroll
    for (int nt = 0; nt < 4; ++nt)
        tsq_l[nt] = t_sq[j0 + n_base + nt * 16 + row16];

    #pragma unroll
    for (int mt = 0; mt < 4; ++mt) {
        #pragma unroll
        for (int r = 0; r < 4; ++r) {
            const int i = i0 + m_base + mt * 16 + quad * 4 + r;
            const float psq = p_sq[i];
            const float c0  = -diagl[i] * LOG2E;  // -logit_ii in log2 domain
            float sfin = 0.f;
            #pragma unroll
            for (int nt = 0; nt < 4; ++nt) {
                float c  = acc[mt][nt][r];
                float sq = fmaxf(fmaf(-2.0f, c, psq + tsq_l[nt]), 0.0f);
                float d  = sqrtf(sq);
                float y  = fmaf(d, NT_LOG2E, c0);  // (logit-logit_ii)*log2e
                sfin += exp2f(y);
            }
            #pragma unroll
            for (int m = 1; m < 16; m <<= 1) sfin += __shfl_xor(sfin, m, 64);
            if (row16 == 0) atomicAdd(&rowsum[i], sfin);
        }
    }

    // Fused finalize: last block to finish reduces rowsum -> 3 scalars.
    // rowsum is only ever touched by device-scope atomics (adds above, reads
    // below via atomicAdd(p, 0)) -> coherent across XCDs at the atomic point.
    __threadfence();
    __shared__ unsigned int lastflag;
    if (tid == 0) {
        unsigned int old = atomicAdd(counter, 1u);
        lastflag = (old == (unsigned)(GRID_TILES - 1)) ? 1u : 0u;
    }
    __syncthreads();
    if (lastflag) {
        double sc = 0.0, sm = 0.0;
        for (int i = tid; i < B_ROWS; i += 256) {
            float rs = atomicAdd(&rowsum[i], 0.0f);   // coherent read
            sc += log((double)rs);
            sm += (double)magr[i];
        }
        #pragma unroll
        for (int m = 1; m < 64; m <<= 1) {
            sc += __shfl_xor(sc, m, 64);
            sm += __shfl_xor(sm, m, 64);
        }
        __shared__ double red[4][2];
        if ((tid & 63) == 0) { red[tid >> 6][0] = sc; red[tid >> 6][1] = sm; }
        __syncthreads();
        if (tid == 0) {
            sc = red[0][0] + red[1][0] + red[2][0] + red[3][0];
            sm = red[0][1] + red[1][1] + red[2][1] + red[3][1];
            double lc = sc / (double)B_ROWS;
            double lm = sm / (double)B_ROWS;
            out[0] = (float)(0.5 * lc + 0.5 * lm);  // LOSS_SCALE=1, LAMBD=0.5
            out[1] = (float)lc;
            out[2] = (float)lm;
        }
    }
}

extern "C" void kernel_launch(void* const* d_in, const int* in_sizes, int n_in,
                              void* d_out, int out_size, void* d_ws, size_t ws_size,
                              hipStream_t stream) {
    const float* P = (const float*)d_in[0];   // predicted [4096,768] fp32
    const float* T = (const float*)d_in[1];   // target    [4096,768] fp32
    float* out = (float*)d_out;               // 3 fp32 scalars

    char* ws = (char*)d_ws;
    float* rowsum = (float*)ws;               ws += B_ROWS * sizeof(float);
    float* p_sq   = (float*)ws;               ws += B_ROWS * sizeof(float);
    float* t_sq   = (float*)ws;               ws += B_ROWS * sizeof(float);
    float* diagl  = (float*)ws;               ws += B_ROWS * sizeof(float);
    float* magr   = (float*)ws;               ws += B_ROWS * sizeof(float);
    unsigned int* counter = (unsigned int*)ws; ws += 16;  // keep 16B align
    unsigned short* Pb = (unsigned short*)ws; ws += (size_t)B_ROWS * D_DIM * 2;
    unsigned short* Tb = (unsigned short*)ws;

    rowstats_kernel<<<B_ROWS / 4, 256, 0, stream>>>(
        P, T, Pb, Tb, p_sq, t_sq, diagl, magr, rowsum, counter);
    lse_gemm_kernel<<<dim3(NBLK, NBLK), 256, 0, stream>>>(
        Pb, Tb, p_sq, t_sq, diagl, magr, rowsum, counter, out);
}

// Round 5
// 197.868 us; speedup vs baseline: 1.4582x; 1.4582x over previous
//
#include <hip/hip_runtime.h>
#include <hip/hip_bf16.h>
#include <math.h>

// Problem constants (B=4096 rows, D=768 features)
#define B_ROWS 4096
#define D_DIM  768

#define BM 128
#define BN 128
#define BK 64              // 64 bf16 = 128 B per tile row = 8 x 16B chunks
#define NKT (D_DIM / BK)   // 12 K-tiles
#define NBLK (B_ROWS / BM) // 32 tile-blocks per dim
#define GRID_TILES (NBLK * NBLK)

typedef __attribute__((ext_vector_type(8))) short bf16x8;  // 8 bf16 = 4 VGPRs (MFMA A/B frag)
typedef __attribute__((ext_vector_type(4))) float f32x4;   // MFMA C/D frag

__device__ __forceinline__ unsigned short f32_to_bf16(float x) {
    // round-to-nearest-even; inputs are finite normals
    unsigned int u = __float_as_uint(x);
    return (unsigned short)((u + 0x7fffu + ((u >> 16) & 1u)) >> 16);
}

// K1: per-row stats + fp32->bf16 conversion. One WAVE per row (4 rows/block).
__global__ void __launch_bounds__(256) rowstats_kernel(
    const float* __restrict__ P, const float* __restrict__ T,
    unsigned short* __restrict__ Pb, unsigned short* __restrict__ Tb,
    float* __restrict__ p_sq, float* __restrict__ t_sq,
    float* __restrict__ diagl, float* __restrict__ magr,
    float* __restrict__ rowsum, unsigned int* __restrict__ counter)
{
    if (blockIdx.x == 0 && threadIdx.x == 0) *counter = 0u;
    const int wave = threadIdx.x >> 6, lane = threadIdx.x & 63;
    const int i = blockIdx.x * 4 + wave;
    const f32x4* prow = (const f32x4*)(P + (size_t)i * D_DIM);
    const f32x4* trow = (const f32x4*)(T + (size_t)i * D_DIM);
    ushort4* pbrow = (ushort4*)(Pb + (size_t)i * D_DIM);
    ushort4* tbrow = (ushort4*)(Tb + (size_t)i * D_DIM);

    float psq = 0.f, tsq = 0.f, cr = 0.f, l1 = 0.f, tm = 0.f;
    #pragma unroll
    for (int u = 0; u < 3; ++u) {         // 192 float4 per row / 64 lanes
        const int c4 = u * 64 + lane;
        f32x4 p = prow[c4], t = trow[c4];
        #pragma unroll
        for (int k = 0; k < 4; ++k) {
            psq += p[k] * p[k]; tsq += t[k] * t[k]; cr += p[k] * t[k];
            l1 += fabsf(p[k] - t[k]); tm += fabsf(t[k]);
        }
        pbrow[c4] = make_ushort4(f32_to_bf16(p[0]), f32_to_bf16(p[1]),
                                 f32_to_bf16(p[2]), f32_to_bf16(p[3]));
        tbrow[c4] = make_ushort4(f32_to_bf16(t[0]), f32_to_bf16(t[1]),
                                 f32_to_bf16(t[2]), f32_to_bf16(t[3]));
    }
    #pragma unroll
    for (int m = 1; m < 64; m <<= 1) {
        psq += __shfl_xor(psq, m, 64);
        tsq += __shfl_xor(tsq, m, 64);
        cr  += __shfl_xor(cr,  m, 64);
        l1  += __shfl_xor(l1,  m, 64);
        tm  += __shfl_xor(tm,  m, 64);
    }
    if (lane == 0) {
        p_sq[i] = psq;
        t_sq[i] = tsq;
        float sq = fmaxf(psq + tsq - 2.0f * cr, 0.0f);
        diagl[i] = -sqrtf(sq) * 10.0f;    // logit_ii = -dist/0.1 (the LSE shift)
        magr[i]  = l1 / tm;
        rowsum[i] = 0.0f;
    }
}

// K2: bf16-MFMA cross GEMM (128x128 tile) + shifted-exp row-sum epilogue
// + fused final reduction (last block).
//
// K-loop: global->VGPR prefetch + ds_write (vmcnt wait lands after a full
// compute phase, not at the barrier). Barriers drain only lgkmcnt.
//   load(0)->regs
//   loop: [barrier] ds_write regs; load(kt+1)->regs; barrier; compute(kt)
//
// __launch_bounds__(256, 2): R4 lesson — with 32KB LDS the backend targets
// 4 waves/EU -> ~128-VGPR budget -> spills the staging regs to scratch
// (WRITE_SIZE 4MB->284MB, 4x slowdown). Pinning 2 waves/EU allows 256 VGPRs
// (2 blocks/CU, same occupancy as measured in R2/R3) and kills the spill.
//
// LDS chunk-XOR swizzle (slot = chunk ^ row&7, 16B units): 0 bank conflicts
// for both ds_write_b128 and ds_read_b128 (verified R2-R4).
__global__ void __launch_bounds__(256, 2) lse_gemm_kernel(
    const unsigned short* __restrict__ Pb, const unsigned short* __restrict__ Tb,
    const float* __restrict__ p_sq, const float* __restrict__ t_sq,
    const float* __restrict__ diagl, const float* __restrict__ magr,
    float* __restrict__ rowsum, unsigned int* __restrict__ counter,
    float* __restrict__ out)
{
    __shared__ __align__(16) unsigned short As[BM * BK];  // 16 KB
    __shared__ __align__(16) unsigned short Bs[BN * BK];  // 16 KB

    const int tid = threadIdx.x;

    // XCD-aware swizzle: HW round-robins linear wg id over 8 XCDs (flat%8).
    // Group 8x8 tiles (3.1 MB working set < 4 MiB L2) onto one XCD.
    const int flat = blockIdx.y * NBLK + blockIdx.x;
    const int xcd  = flat & 7;
    const int s    = flat >> 3;                 // 0..127: slot within XCD
    const int g    = xcd + ((s >> 6) << 3);     // group 0..15
    const int w    = s & 63;                    // tile within 8x8 group
    const int i0   = (((g >> 2) << 3) + (w >> 3)) * BM;  // P row block
    const int j0   = (((g & 3) << 3) + (w & 7)) * BN;    // T row block

    const int lane  = tid & 63;
    const int wave  = tid >> 6;
    const int wm    = wave >> 1, wn = wave & 1;    // 2x2 wave grid
    const int row16 = lane & 15, quad = lane >> 4;
    const int m_base = wm * 64, n_base = wn * 64;
    const int swz = (quad ^ (row16 & 7)) << 4;  // ds_read swizzled byte offset

    // staging map: thread covers rows r0+32*it (it=0..3), chunk c8 (16B) of
    // each row; writes it to swizzled LDS slot c8 ^ (row&7).
    const int c8 = tid & 7;            // chunk column 0..7
    const int r0 = tid >> 3;           // base row 0..31
    const int sw = c8 ^ (r0 & 7);      // (32*it doesn't change row&7)
    const int4* gpA = (const int4*)Pb + (size_t)(i0 + r0) * (D_DIM / 8) + c8;
    const int4* gpB = (const int4*)Tb + (size_t)(j0 + r0) * (D_DIM / 8) + c8;
    int4* lwA = (int4*)&As[r0 * 64 + sw * 8];   // +it*256 (int4) per 32 rows
    int4* lwB = (int4*)&Bs[r0 * 64 + sw * 8];

    f32x4 acc[4][4];
    #pragma unroll
    for (int a = 0; a < 4; ++a)
        #pragma unroll
        for (int b = 0; b < 4; ++b)
            acc[a][b] = (f32x4){0.f, 0.f, 0.f, 0.f};

    // staging registers as scalars (defensive vs array->scratch demotion)
    int4 pA0 = gpA[0],    pA1 = gpA[3072], pA2 = gpA[6144], pA3 = gpA[9216];
    int4 tB0 = gpB[0],    tB1 = gpB[3072], tB2 = gpB[6144], tB3 = gpB[9216];

    const char* Ab = (const char*)As;
    const char* Bb = (const char*)Bs;

    for (int ktile = 0; ktile < NKT; ++ktile) {
        if (ktile) __syncthreads();   // all waves done reading LDS (lgkm only)
        lwA[0]   = pA0;  lwA[256] = pA1;  lwA[512] = pA2;  lwA[768] = pA3;
        lwB[0]   = tB0;  lwB[256] = tB1;  lwB[512] = tB2;  lwB[768] = tB3;
        if (ktile + 1 < NKT) {                  // prefetch next tile -> regs
            const int ko = (ktile + 1) * 8;     // 8 int4 per BK step
            pA0 = gpA[ko];        pA1 = gpA[3072 + ko];
            pA2 = gpA[6144 + ko]; pA3 = gpA[9216 + ko];
            tB0 = gpB[ko];        tB1 = gpB[3072 + ko];
            tB2 = gpB[6144 + ko]; tB3 = gpB[9216 + ko];
        }
        __syncthreads();                        // LDS writes visible

        #pragma unroll
        for (int ks = 0; ks < BK; ks += 32) {
            const int kx = ks ? 64 : 0;   // chunk+4 == slot^4 == byte addr^64
            bf16x8 a[4], b[4];
            #pragma unroll
            for (int mt = 0; mt < 4; ++mt) {
                const int off = (m_base + mt * 16 + row16) * 128 + swz;
                a[mt] = *(const bf16x8*)(Ab + (off ^ kx));
            }
            #pragma unroll
            for (int nt = 0; nt < 4; ++nt) {
                const int off = (n_base + nt * 16 + row16) * 128 + swz;
                b[nt] = *(const bf16x8*)(Bb + (off ^ kx));
            }
            #pragma unroll
            for (int mt = 0; mt < 4; ++mt)
                #pragma unroll
                for (int nt = 0; nt < 4; ++nt)
                    acc[mt][nt] = __builtin_amdgcn_mfma_f32_16x16x32_bf16(
                        a[mt], b[nt], acc[mt][nt], 0, 0, 0);
        }
    }

    // Epilogue: C/D layout col=lane&15, row=quad*4+reg (m89/m91-verified).
    // term = exp(logit_ij - logit_ii) via exp2f; max shifted log2-exp ~99 < 127.
    const float NT_LOG2E = -14.4269504089f;   // -(1/TEMP) * log2(e)
    const float LOG2E    = 1.44269504089f;
    float tsq_l[4];
    #pragma unroll
    for (int nt = 0; nt < 4; ++nt)
        tsq_l[nt] = t_sq[j0 + n_base + nt * 16 + row16];

    #pragma unroll
    for (int mt = 0; mt < 4; ++mt) {
        #pragma unroll
        for (int r = 0; r < 4; ++r) {
            const int i = i0 + m_base + mt * 16 + quad * 4 + r;
            const float psq = p_sq[i];
            const float c0  = -diagl[i] * LOG2E;  // -logit_ii in log2 domain
            float sfin = 0.f;
            #pragma unroll
            for (int nt = 0; nt < 4; ++nt) {
                float c  = acc[mt][nt][r];
                float sq = fmaxf(fmaf(-2.0f, c, psq + tsq_l[nt]), 0.0f);
                float d  = sqrtf(sq);
                float y  = fmaf(d, NT_LOG2E, c0);  // (logit-logit_ii)*log2e
                sfin += exp2f(y);
            }
            #pragma unroll
            for (int m = 1; m < 16; m <<= 1) sfin += __shfl_xor(sfin, m, 64);
            if (row16 == 0) atomicAdd(&rowsum[i], sfin);
        }
    }

    // Fused finalize: last block to finish reduces rowsum -> 3 scalars.
    // rowsum is only ever touched by device-scope atomics (adds above, reads
    // below via atomicAdd(p, 0)) -> coherent across XCDs at the atomic point.
    __threadfence();
    __shared__ unsigned int lastflag;
    if (tid == 0) {
        unsigned int old = atomicAdd(counter, 1u);
        lastflag = (old == (unsigned)(GRID_TILES - 1)) ? 1u : 0u;
    }
    __syncthreads();
    if (lastflag) {
        double sc = 0.0, sm = 0.0;
        for (int i = tid; i < B_ROWS; i += 256) {
            float rs = atomicAdd(&rowsum[i], 0.0f);   // coherent read
            sc += log((double)rs);
            sm += (double)magr[i];
        }
        #pragma unroll
        for (int m = 1; m < 64; m <<= 1) {
            sc += __shfl_xor(sc, m, 64);
            sm += __shfl_xor(sm, m, 64);
        }
        __shared__ double red[4][2];
        if ((tid & 63) == 0) { red[tid >> 6][0] = sc; red[tid >> 6][1] = sm; }
        __syncthreads();
        if (tid == 0) {
            sc = red[0][0] + red[1][0] + red[2][0] + red[3][0];
            sm = red[0][1] + red[1][1] + red[2][1] + red[3][1];
            double lc = sc / (double)B_ROWS;
            double lm = sm / (double)B_ROWS;
            out[0] = (float)(0.5 * lc + 0.5 * lm);  // LOSS_SCALE=1, LAMBD=0.5
            out[1] = (float)lc;
            out[2] = (float)lm;
        }
    }
}

extern "C" void kernel_launch(void* const* d_in, const int* in_sizes, int n_in,
                              void* d_out, int out_size, void* d_ws, size_t ws_size,
                              hipStream_t stream) {
    const float* P = (const float*)d_in[0];   // predicted [4096,768] fp32
    const float* T = (const float*)d_in[1];   // target    [4096,768] fp32
    float* out = (float*)d_out;               // 3 fp32 scalars

    char* ws = (char*)d_ws;
    float* rowsum = (float*)ws;               ws += B_ROWS * sizeof(float);
    float* p_sq   = (float*)ws;               ws += B_ROWS * sizeof(float);
    float* t_sq   = (float*)ws;               ws += B_ROWS * sizeof(float);
    float* diagl  = (float*)ws;               ws += B_ROWS * sizeof(float);
    float* magr   = (float*)ws;               ws += B_ROWS * sizeof(float);
    unsigned int* counter = (unsigned int*)ws; ws += 16;  // keep 16B align
    unsigned short* Pb = (unsigned short*)ws; ws += (size_t)B_ROWS * D_DIM * 2;
    unsigned short* Tb = (unsigned short*)ws;

    rowstats_kernel<<<B_ROWS / 4, 256, 0, stream>>>(
        P, T, Pb, Tb, p_sq, t_sq, diagl, magr, rowsum, counter);
    lse_gemm_kernel<<<dim3(NBLK, NBLK), 256, 0, stream>>>(
        Pb, Tb, p_sq, t_sq, diagl, magr, rowsum, counter, out);
}